// Round 4
// baseline (2612.272 us; speedup 1.0000x reference)
//
#include <hip/hip_runtime.h>
#include <stdint.h>

// Borůvka maximum-spanning-forest == Kruskal acceptance set under the strict
// total order (score desc, edge-index asc). Multi-launch (kernel boundaries =
// cheap barrier; coop grid.sync measured 2.3x slower, R2). All round kernels
// are record-domain: a survivor record carries (key, rootA, rootB), so scan
// needs no src/dst gathers and root lookup is a single L2-resident load.
#define V_NODES 100000
#define MAX_ROUNDS 17   // components at least halve per round; 2^17 > 1e5

struct alignas(16) Rec { unsigned long long k; unsigned int a, b; };

// key = (~monotone_f32(score) << 32) | edge_id — min-key == best edge
// (largest score, ties -> smallest index, matching stable argsort(-scores)).
__device__ __forceinline__ unsigned long long make_key(float sv, float uv, int id) {
    float sp = 1.0f / (1.0f + expf(-sv));                 // sigmoid, f32 chain
    float g  = -logf(-logf(uv + 1e-9f) + 1e-9f);          // gumbel, f32 chain
    unsigned int b = __float_as_uint(sp + g);
    unsigned int m = (b & 0x80000000u) ? ~b : (b | 0x80000000u);
    return ((unsigned long long)(~m) << 32) | (unsigned int)id;
}

__device__ __forceinline__ void wave_append(bool keep, const Rec& r,
                                            Rec* __restrict__ wlist,
                                            int* __restrict__ wcnt, int lane) {
    unsigned long long mask = __ballot(keep);
    if (!mask) return;
    int leader = __ffsll(mask) - 1;
    int base = 0;
    if (lane == leader) base = atomicAdd(wcnt, __popcll(mask));
    base = __shfl(base, leader);
    if (keep) wlist[base + __popcll(mask & ((1ULL << lane) - 1ULL))] = r;
}

__global__ void k_init(int* __restrict__ parent, unsigned long long* __restrict__ best,
                       int* __restrict__ counts) {
    int v = blockIdx.x * blockDim.x + threadIdx.x;
    if (v < MAX_ROUNDS) counts[v] = 0;
    if (v >= V_NODES) return;
    parent[v] = v;
    best[v] = ~0ULL;
}

// Round 0: roots are the raw vertices. Compute keys once, zero out[], bid,
// emit records for round 1.
__global__ void k_scan0(const float* __restrict__ s, const float* __restrict__ u,
                        const int* __restrict__ src, const int* __restrict__ dst,
                        float* __restrict__ out, unsigned long long* __restrict__ best,
                        Rec* __restrict__ wlist, int* __restrict__ wcnt, int E) {
    int e = blockIdx.x * blockDim.x + threadIdx.x;
    int lane = threadIdx.x & 63;
    bool keep = false;
    Rec r;
    if (e < E) {
        out[e] = 0.0f;                       // harness poisons d_out each call
        unsigned int a = src[e], b = dst[e];
        if (a != b) {                        // self-loops never accepted
            keep = true;
            r.k = make_key(s[e], u[e], e); r.a = a; r.b = b;
            if (r.k < __hip_atomic_load(&best[a], __ATOMIC_RELAXED, __HIP_MEMORY_SCOPE_AGENT))
                atomicMin(&best[a], r.k);
            if (r.k < __hip_atomic_load(&best[b], __ATOMIC_RELAXED, __HIP_MEMORY_SCOPE_AGENT))
                atomicMin(&best[b], r.k);
        }
    }
    wave_append(keep, r, wlist, wcnt, lane);
}

// Rounds >=1: record endpoints are previous-round roots, compressed, so
// parent[a] IS the current root (single load into 0.4MB L2-resident array).
__global__ void k_scan(const int* __restrict__ parent,
                       unsigned long long* __restrict__ best,
                       const Rec* __restrict__ rlist, Rec* __restrict__ wlist,
                       const int* __restrict__ rcnt, int* __restrict__ wcnt) {
    int n = *rcnt;
    int i = blockIdx.x * blockDim.x + threadIdx.x;
    int lane = threadIdx.x & 63;
    bool keep = false;
    Rec r;
    if (i < n) {
        r = rlist[i];
        unsigned int ra = (unsigned int)parent[r.a];
        unsigned int rb = (unsigned int)parent[r.b];
        if (ra != rb) {
            keep = true;
            r.a = ra; r.b = rb;
            if (r.k < __hip_atomic_load(&best[ra], __ATOMIC_RELAXED, __HIP_MEMORY_SCOPE_AGENT))
                atomicMin(&best[ra], r.k);   // check-before-atomic: late rounds
            if (r.k < __hip_atomic_load(&best[rb], __ATOMIC_RELAXED, __HIP_MEMORY_SCOPE_AGENT))
                atomicMin(&best[rb], r.k);   // become broadcast reads
        }
    }
    wave_append(keep, r, wlist, wcnt, lane);
}

// A record is root a's unique winner iff best[a]==k (key embeds edge id).
// Winner thread marks the edge (cut property => in MSF) and hooks directly:
// parent writes are race-free (unique winner per root); mutual pair (both
// roots chose this same edge) broken by root id; hook chains follow strictly
// decreasing keys => acyclic.
__global__ void k_merge(const Rec* __restrict__ list, const int* __restrict__ cnt,
                        const unsigned long long* __restrict__ best,
                        int* __restrict__ parent, float* __restrict__ out) {
    int n = *cnt;
    int i = blockIdx.x * blockDim.x + threadIdx.x;
    if (i >= n) return;
    Rec r = list[i];
    bool wa = (best[r.a] == r.k);
    bool wb = (best[r.b] == r.k);
    if (wa || wb) out[(unsigned int)(r.k & 0xffffffffu)] = 1.0f;
    if (wa && (!wb || r.a > r.b)) parent[r.a] = (int)r.b;
    if (wb && (!wa || r.b > r.a)) parent[r.b] = (int)r.a;
}

// Compress exactly the parents the next round will read (record endpoints),
// and reset their best. Duplicate work across records sharing endpoints is
// benign (same final values); concurrent parent writes only move toward the
// fixed root set (no hooks happen in this kernel).
__global__ void k_compress(const Rec* __restrict__ list, const int* __restrict__ cnt,
                           int* __restrict__ parent, unsigned long long* __restrict__ best) {
    int n = *cnt;
    int i = blockIdx.x * blockDim.x + threadIdx.x;
    if (i >= n) return;
    Rec r = list[i];
    int p = parent[r.a];
    int pp = parent[p];
    while (p != pp) { p = pp; pp = parent[p]; }
    parent[r.a] = p;
    best[r.a] = ~0ULL;
    p = parent[r.b];
    pp = parent[p];
    while (p != pp) { p = pp; pp = parent[p]; }
    parent[r.b] = p;
    best[r.b] = ~0ULL;
}

extern "C" void kernel_launch(void* const* d_in, const int* in_sizes, int n_in,
                              void* d_out, int out_size, void* d_ws, size_t ws_size,
                              hipStream_t stream) {
    const float* s  = (const float*)d_in[0];
    const float* u  = (const float*)d_in[1];
    const int*   ei = (const int*)d_in[2];
    const int E = in_sizes[0];
    const int* src = ei;
    const int* dst = ei + E;
    float* out = (float*)d_out;

    char* ws = (char*)d_ws;                                   // 16B-aligned
    Rec* bufA = (Rec*)ws;                                     // E*16 = 6.4 MB
    Rec* bufB = bufA + E;                                     // E*16 = 6.4 MB
    unsigned long long* best = (unsigned long long*)(bufB + E); // V*8
    int* parent = (int*)(best + V_NODES);                     // V*4
    int* counts = parent + V_NODES;                           // MAX_ROUNDS*4
    // total ~14.2 MB

    const int tb = 256;
    const int gE = (E + tb - 1) / tb;
    const int gV = (V_NODES + tb - 1) / tb;

    k_init<<<gV, tb, 0, stream>>>(parent, best, counts);
    k_scan0<<<gE, tb, 0, stream>>>(s, u, src, dst, out, best, bufA, counts, E);
    k_merge<<<gE, tb, 0, stream>>>(bufA, counts, best, parent, out);
    k_compress<<<gE, tb, 0, stream>>>(bufA, counts, parent, best);

    for (int r = 1; r < MAX_ROUNDS; ++r) {
        const Rec* rl = (r & 1) ? bufA : bufB;
        Rec*       wl = (r & 1) ? bufB : bufA;
        k_scan<<<gE, tb, 0, stream>>>(parent, best, rl, wl, counts + r - 1, counts + r);
        k_merge<<<gE, tb, 0, stream>>>(wl, counts + r, best, parent, out);
        k_compress<<<gE, tb, 0, stream>>>(wl, counts + r, parent, best);
    }
}

// Round 5
// 1075.324 us; speedup vs baseline: 2.4293x; 2.4293x over previous
//
#include <hip/hip_runtime.h>
#include <stdint.h>

// Borůvka maximum-spanning-forest == Kruskal acceptance set under the strict
// total order (score desc, edge-index asc). Multi-launch (kernel boundary =
// cheap barrier; coop grid.sync measured 2.3x slower, R2). Two kernels per
// round: record-domain scan (bid + compact + path-shortcut + prev-best reset)
// and V-domain choose (winner mark + hook). best[] ping-pongs between rounds
// so no separate reset pass is needed; stale entries are provably benign
// (they resolve to other==v => no hook, redundant out-write of 1).
#define V_NODES 100000
#define MAX_ROUNDS 17     // components at least halve per round; 2^17 > 1e5
#define SCAN_BLOCKS 512
#define TB 256

struct alignas(16) Rec { unsigned long long k; unsigned int a, b; };

// key = (~monotone_f32(score) << 32) | edge_id — min-key == best edge
// (largest score, ties -> smallest index, matching stable argsort(-scores)).
__device__ __forceinline__ unsigned long long make_key(float sv, float uv, int id) {
    float sp = 1.0f / (1.0f + expf(-sv));                 // sigmoid, f32 chain
    float g  = -logf(-logf(uv + 1e-9f) + 1e-9f);          // gumbel, f32 chain
    unsigned int b = __float_as_uint(sp + g);
    unsigned int m = (b & 0x80000000u) ? ~b : (b | 0x80000000u);
    return ((unsigned long long)(~m) << 32) | (unsigned int)id;
}

// Chase to current root; races with concurrent hooks/shortcuts are safe
// (pointers only move toward the final root; 2-cycles are tie-broken away).
__device__ __forceinline__ int find_root(int* __restrict__ parent, int v) {
    int p = parent[v];
    int pp = parent[p];
    while (p != pp) { p = pp; pp = parent[p]; }
    return p;
}

__device__ __forceinline__ void wave_append(bool keep, const Rec& r,
                                            Rec* __restrict__ wlist,
                                            int* __restrict__ wcnt, int lane) {
    unsigned long long mask = __ballot(keep);
    if (!mask) return;
    int leader = __ffsll(mask) - 1;
    int base = 0;
    if (lane == leader) base = atomicAdd(wcnt, __popcll(mask));
    base = __shfl(base, leader);
    if (keep) wlist[base + __popcll(mask & ((1ULL << lane) - 1ULL))] = r;
}

__global__ void k_init(int* __restrict__ parent, unsigned long long* __restrict__ bestA,
                       unsigned long long* __restrict__ bestB, int* __restrict__ counts) {
    int v = blockIdx.x * blockDim.x + threadIdx.x;
    if (v < MAX_ROUNDS) counts[v] = 0;
    if (v >= V_NODES) return;
    parent[v] = v;
    bestA[v] = ~0ULL;
    bestB[v] = ~0ULL;
}

// Round 0: endpoints ARE roots. Compute keys once, zero out[], bid into bestA,
// emit (key, a, b) records for round 1.
__global__ void k_scan0(const float* __restrict__ s, const float* __restrict__ u,
                        const int* __restrict__ src, const int* __restrict__ dst,
                        float* __restrict__ out, unsigned long long* __restrict__ best,
                        Rec* __restrict__ wlist, int* __restrict__ wcnt, int E) {
    int e = blockIdx.x * blockDim.x + threadIdx.x;
    int lane = threadIdx.x & 63;
    bool keep = false;
    Rec r;
    if (e < E) {
        out[e] = 0.0f;                       // harness poisons d_out each call
        unsigned int a = src[e], b = dst[e];
        if (a != b) {                        // self-loops never accepted
            keep = true;
            r.k = make_key(s[e], u[e], e); r.a = a; r.b = b;
            if (r.k < __hip_atomic_load(&best[a], __ATOMIC_RELAXED, __HIP_MEMORY_SCOPE_AGENT))
                atomicMin(&best[a], r.k);
            if (r.k < __hip_atomic_load(&best[b], __ATOMIC_RELAXED, __HIP_MEMORY_SCOPE_AGENT))
                atomicMin(&best[b], r.k);
        }
    }
    wave_append(keep, r, wlist, wcnt, lane);
}

// Rounds >=1. Grid-stride persistent sweep; record endpoints are old roots so
// chains are 1-2 hops (shortcut stores below keep them short). Resets the
// PREVIOUS round's best entries for every root it touches (ping-pong).
__global__ void k_scan(int* __restrict__ parent,
                       unsigned long long* __restrict__ bestC,
                       unsigned long long* __restrict__ bestP,
                       const Rec* __restrict__ rlist, Rec* __restrict__ wlist,
                       const int* __restrict__ rcnt, int* __restrict__ wcnt) {
    int n = *rcnt;
    int lane = threadIdx.x & 63;
    const int stride = SCAN_BLOCKS * TB;
    for (int i = blockIdx.x * TB + threadIdx.x; __any(i < n); i += stride) {
        bool keep = false;
        Rec r;
        if (i < n) {
            r = rlist[i];
            int ra = find_root(parent, (int)r.a);
            int rb = find_root(parent, (int)r.b);
            if (ra != (int)r.a) parent[r.a] = ra;   // path shortcut for next round
            if (rb != (int)r.b) parent[r.b] = rb;
            if (ra != rb) {
                keep = true;
                r.a = (unsigned int)ra; r.b = (unsigned int)rb;
                bestP[ra] = ~0ULL;                  // reset prev-round best
                bestP[rb] = ~0ULL;
                if (r.k < __hip_atomic_load(&bestC[ra], __ATOMIC_RELAXED, __HIP_MEMORY_SCOPE_AGENT))
                    atomicMin(&bestC[ra], r.k);     // check-before-atomic
                if (r.k < __hip_atomic_load(&bestC[rb], __ATOMIC_RELAXED, __HIP_MEMORY_SCOPE_AGENT))
                    atomicMin(&bestC[rb], r.k);
            }
        }
        wave_append(keep, r, wlist, wcnt, lane);
    }
}

// V-domain winner/hook. v's winning record is unique (key embeds edge id):
// mark the edge (cut property => in MSF) and hook v into the partner's tree.
// Mutual pair broken by root id. Concurrent hooks may deepen find_root
// results; acyclicity still holds (key-chain argument), and stale best
// entries resolve to other==v => no hook.
__global__ void k_choose(const int* __restrict__ src, const int* __restrict__ dst,
                         int* __restrict__ parent,
                         const unsigned long long* __restrict__ bestC,
                         float* __restrict__ out, const int* __restrict__ cnt) {
    if (*cnt == 0) return;   // no crossing records => no bids => nothing to do
    int v = blockIdx.x * blockDim.x + threadIdx.x;
    if (v >= V_NODES) return;
    unsigned long long k = bestC[v];
    if (k == ~0ULL) return;
    int id = (int)(unsigned int)(k & 0xffffffffu);
    int a0 = src[id], b0 = dst[id];
    int ru = find_root(parent, a0);
    int rv = find_root(parent, b0);
    if (ru != a0) parent[a0] = ru;          // shortcut original-vertex chains
    if (rv != b0) parent[b0] = rv;
    int other = (ru == v) ? rv : ru;
    out[id] = 1.0f;
    if (bestC[other] != k || v > other) {   // not mutual, or id tie-break won
        if (other != v) parent[v] = other;
    }
}

extern "C" void kernel_launch(void* const* d_in, const int* in_sizes, int n_in,
                              void* d_out, int out_size, void* d_ws, size_t ws_size,
                              hipStream_t stream) {
    const float* s  = (const float*)d_in[0];
    const float* u  = (const float*)d_in[1];
    const int*   ei = (const int*)d_in[2];
    const int E = in_sizes[0];
    const int* src = ei;
    const int* dst = ei + E;
    float* out = (float*)d_out;

    char* ws = (char*)d_ws;                                     // 16B-aligned
    Rec* bufA = (Rec*)ws;                                       // E*16 = 6.4 MB
    Rec* bufB = bufA + E;                                       // E*16 = 6.4 MB
    unsigned long long* bestA = (unsigned long long*)(bufB + E); // V*8
    unsigned long long* bestB = bestA + V_NODES;                // V*8
    int* parent = (int*)(bestB + V_NODES);                      // V*4
    int* counts = parent + V_NODES;                             // MAX_ROUNDS*4
    // total ~14.9 MB (R4 used 14.2 MB successfully)

    const int gE = (E + TB - 1) / TB;
    const int gV = (V_NODES + TB - 1) / TB;

    k_init<<<gV, TB, 0, stream>>>(parent, bestA, bestB, counts);
    k_scan0<<<gE, TB, 0, stream>>>(s, u, src, dst, out, bestA, bufA, counts, E);
    k_choose<<<gV, TB, 0, stream>>>(src, dst, parent, bestA, out, counts);

    for (int r = 1; r < MAX_ROUNDS; ++r) {
        const Rec* rl = (r & 1) ? bufA : bufB;
        Rec*       wl = (r & 1) ? bufB : bufA;
        unsigned long long* bc = (r & 1) ? bestB : bestA;   // bid target this round
        unsigned long long* bp = (r & 1) ? bestA : bestB;   // reset (prev round's)
        k_scan<<<SCAN_BLOCKS, TB, 0, stream>>>(parent, bc, bp, rl, wl,
                                               counts + r - 1, counts + r);
        k_choose<<<gV, TB, 0, stream>>>(src, dst, parent, bc, out, counts + r);
    }
}

// Round 7
// 1002.602 us; speedup vs baseline: 2.6055x; 1.0725x over previous
//
#include <hip/hip_runtime.h>
#include <stdint.h>

// Borůvka maximum-spanning-forest == Kruskal acceptance set under the strict
// total order (score desc, edge-index asc). Multi-launch (kernel boundary =
// cheap barrier; coop grid.sync measured 2.3x slower, R2). Two kernels per
// round (scan: bid; choose: winner mark + hook) — the two barriers per round
// are fundamental (bids need hooks applied; winners need all bids).
//
// R6 structure: NO compaction (records die too slowly on random graphs to pay
// for a 6.4MB list write + a single-line wcnt atomic hot-spot per round —
// measured R5). Records are updated IN PLACE: endpoints rewritten to current
// roots when changed, marked dead (a==b) when internal. flags[r] gates idle
// rounds down to launch overhead. best[] ping-pongs between rounds; in-scan
// reset of the previous buffer is REQUIRED (a stale winning key whose edge
// went internal would block future bids for that root => livelock).
#define V_NODES 100000
#define MAX_ROUNDS 17   // components at least halve per active round; 2^17 > 1e5
#define TB 256

struct alignas(16) Rec { unsigned long long k; unsigned int a, b; };

// key = (~monotone_f32(score) << 32) | edge_id — min-key == best edge
// (largest score, ties -> smallest index, matching stable argsort(-scores)).
__device__ __forceinline__ unsigned long long make_key(float sv, float uv, int id) {
    float sp = 1.0f / (1.0f + expf(-sv));                 // sigmoid, f32 chain
    float g  = -logf(-logf(uv + 1e-9f) + 1e-9f);          // gumbel, f32 chain
    unsigned int b = __float_as_uint(sp + g);
    unsigned int m = (b & 0x80000000u) ? ~b : (b | 0x80000000u);
    return ((unsigned long long)(~m) << 32) | (unsigned int)id;
}

// Chase to current root; races with concurrent hooks/shortcuts are safe
// (pointers only move toward the final root; 2-cycles are tie-broken away).
__device__ __forceinline__ int find_root(const int* __restrict__ parent, int v) {
    int p = parent[v];
    int pp = parent[p];
    while (p != pp) { p = pp; pp = parent[p]; }
    return p;
}

__global__ void k_init(int* __restrict__ parent, unsigned long long* __restrict__ bestA,
                       unsigned long long* __restrict__ bestB, int* __restrict__ flags) {
    int v = blockIdx.x * blockDim.x + threadIdx.x;
    if (v < MAX_ROUNDS) flags[v] = 0;
    if (v >= V_NODES) return;
    parent[v] = v;
    bestA[v] = ~0ULL;
    bestB[v] = ~0ULL;
}

// Round 0: endpoints ARE roots. Compute keys once, zero out[], build the
// record array, bid into bestA. Self-loops are born dead (a==b).
__global__ void k_scan0(const float* __restrict__ s, const float* __restrict__ u,
                        const int* __restrict__ src, const int* __restrict__ dst,
                        float* __restrict__ out, unsigned long long* __restrict__ best,
                        Rec* __restrict__ recs, int* __restrict__ flags, int E) {
    int e = blockIdx.x * blockDim.x + threadIdx.x;
    if (e >= E) return;
    unsigned int a = src[e], b = dst[e];
    Rec r;
    r.k = make_key(s[e], u[e], e);
    r.a = a; r.b = b;
    recs[e] = r;
    out[e] = 0.0f;                           // harness poisons d_out each call
    if (a != b) {
        if (r.k < __hip_atomic_load(&best[a], __ATOMIC_RELAXED, __HIP_MEMORY_SCOPE_AGENT))
            atomicMin(&best[a], r.k);
        if (r.k < __hip_atomic_load(&best[b], __ATOMIC_RELAXED, __HIP_MEMORY_SCOPE_AGENT))
            atomicMin(&best[b], r.k);
    }
    if (e == 0) flags[0] = 1;
}

// Rounds >=1. Record endpoints are previous-round roots => root lookup is
// 1-2 L2-resident loads. Updates records in place (8B store only on change),
// resets the previous round's best entries (ping-pong), bids into bestC.
__global__ void k_scan(const int* __restrict__ parent,
                       unsigned long long* __restrict__ bestC,
                       unsigned long long* __restrict__ bestP,
                       Rec* __restrict__ recs, int* __restrict__ flags,
                       int r, int E) {
    __shared__ int sflag;
    if (flags[r - 1] == 0) return;           // converged: launch-cost only
    if (threadIdx.x == 0) sflag = 0;
    __syncthreads();
    int i = blockIdx.x * blockDim.x + threadIdx.x;
    bool cross = false;
    if (i < E) {
        Rec rec = recs[i];
        if (rec.a != rec.b) {                // not yet internal
            unsigned int ra = (unsigned int)find_root(parent, (int)rec.a);
            unsigned int rb = (unsigned int)find_root(parent, (int)rec.b);
            if (ra == rb) {
                *(uint2*)&recs[i].a = make_uint2(ra, ra);   // kill record
            } else {
                cross = true;
                if (ra != rec.a || rb != rec.b)
                    *(uint2*)&recs[i].a = make_uint2(ra, rb);  // shortcut roots
                bestP[ra] = ~0ULL;           // reset prev-round best (required)
                bestP[rb] = ~0ULL;
                if (rec.k < __hip_atomic_load(&bestC[ra], __ATOMIC_RELAXED, __HIP_MEMORY_SCOPE_AGENT))
                    atomicMin(&bestC[ra], rec.k);   // check-before-atomic
                if (rec.k < __hip_atomic_load(&bestC[rb], __ATOMIC_RELAXED, __HIP_MEMORY_SCOPE_AGENT))
                    atomicMin(&bestC[rb], rec.k);
            }
        }
    }
    if (cross) sflag = 1;                    // LDS race benign (same value)
    __syncthreads();
    if (threadIdx.x == 0 && sflag) flags[r] = 1;   // plain store, 1 per block
}

// V-domain winner/hook. v's winning record is unique (key embeds edge id):
// mark the edge (cut property => in MSF) and hook v into the partner's tree.
// Mutual pair broken by root id; hook chains follow strictly decreasing keys
// => acyclic. Stale best entries (root merged/dead since its bid) resolve to
// a redundant out-write of an already-accepted edge and a benign shortcut.
__global__ void k_choose(const int* __restrict__ src, const int* __restrict__ dst,
                         int* __restrict__ parent,
                         const unsigned long long* __restrict__ bestC,
                         float* __restrict__ out, const int* __restrict__ flags,
                         int r) {
    if (flags[r] == 0) return;               // no bids this round
    int v = blockIdx.x * blockDim.x + threadIdx.x;
    if (v >= V_NODES) return;
    unsigned long long k = bestC[v];
    if (k == ~0ULL) return;
    int id = (int)(unsigned int)(k & 0xffffffffu);
    int a0 = src[id], b0 = dst[id];
    int ru = find_root(parent, a0);
    int rv = find_root(parent, b0);
    if (ru != a0) parent[a0] = ru;           // compress original-vertex chains
    if (rv != b0) parent[b0] = rv;
    int other = (ru == v) ? rv : ru;
    out[id] = 1.0f;
    if (bestC[other] != k || v > other) {    // not mutual, or id tie-break won
        if (other != v) parent[v] = other;
    }
}

extern "C" void kernel_launch(void* const* d_in, const int* in_sizes, int n_in,
                              void* d_out, int out_size, void* d_ws, size_t ws_size,
                              hipStream_t stream) {
    const float* s  = (const float*)d_in[0];
    const float* u  = (const float*)d_in[1];
    const int*   ei = (const int*)d_in[2];
    const int E = in_sizes[0];
    const int* src = ei;
    const int* dst = ei + E;
    float* out = (float*)d_out;

    char* ws = (char*)d_ws;                                      // 16B-aligned
    Rec* recs = (Rec*)ws;                                        // E*16 = 6.4 MB
    unsigned long long* bestA = (unsigned long long*)(recs + E); // V*8
    unsigned long long* bestB = bestA + V_NODES;                 // V*8
    int* parent = (int*)(bestB + V_NODES);                       // V*4
    int* flags  = parent + V_NODES;                              // MAX_ROUNDS*4
    // total ~8.4 MB (R5 used 14.9 MB successfully)

    const int gE = (E + TB - 1) / TB;
    const int gV = (V_NODES + TB - 1) / TB;

    k_init<<<gV, TB, 0, stream>>>(parent, bestA, bestB, flags);
    k_scan0<<<gE, TB, 0, stream>>>(s, u, src, dst, out, bestA, recs, flags, E);
    k_choose<<<gV, TB, 0, stream>>>(src, dst, parent, bestA, out, flags, 0);

    for (int r = 1; r < MAX_ROUNDS; ++r) {
        unsigned long long* bc = (r & 1) ? bestB : bestA;   // bid target
        unsigned long long* bp = (r & 1) ? bestA : bestB;   // reset (prev round)
        k_scan<<<gE, TB, 0, stream>>>(parent, bc, bp, recs, flags, r, E);
        k_choose<<<gV, TB, 0, stream>>>(src, dst, parent, bc, out, flags, r);
    }
}

// Round 8
// 568.113 us; speedup vs baseline: 4.5982x; 1.7648x over previous
//
#include <hip/hip_runtime.h>
#include <stdint.h>

// Borůvka maximum-spanning-forest == Kruskal acceptance set under the strict
// total order (score desc, edge-index asc). Multi-launch (kernel boundary =
// cheap barrier; coop grid.sync measured 2.3x slower, R2). Two kernels per
// round: scan (bid) and choose (winner mark + hook + next-buffer reset).
//
// Structure (R8): no compaction (records die too slowly on random graphs —
// measured R5); records updated IN PLACE (dead => a==b). Scan processes 4
// records/thread with batched independent gathers (latency-bound fix, R7:
// VALUBusy 0.12%, HBM 0.24% => MLP was the limiter). best[] ping-pongs;
// the reset of the idle buffer is a coalesced stream in choose (scattered
// 8B resets in scan thrashed L2 — R7 WRITE_SIZE 6.3MB/scan). The reset is
// REQUIRED (a stale winning key whose edge went internal would block all
// future bids for that root => livelock).
#define V_NODES 100000
#define MAX_ROUNDS 17   // components at least halve per active round; 2^17 > 1e5
#define TB 256
#define RPT 4           // records per scan thread

struct alignas(16) Rec { unsigned long long k; unsigned int a, b; };

// key = (~monotone_f32(score) << 32) | edge_id — min-key == best edge
// (largest score, ties -> smallest index, matching stable argsort(-scores)).
__device__ __forceinline__ unsigned long long make_key(float sv, float uv, int id) {
    float sp = 1.0f / (1.0f + expf(-sv));                 // sigmoid, f32 chain
    float g  = -logf(-logf(uv + 1e-9f) + 1e-9f);          // gumbel, f32 chain
    unsigned int b = __float_as_uint(sp + g);
    unsigned int m = (b & 0x80000000u) ? ~b : (b | 0x80000000u);
    return ((unsigned long long)(~m) << 32) | (unsigned int)id;
}

__device__ __forceinline__ int find_root(const int* __restrict__ parent, int v) {
    int p = parent[v];
    int pp = parent[p];
    while (p != pp) { p = pp; pp = parent[p]; }
    return p;
}

__global__ void k_init(int* __restrict__ parent, unsigned long long* __restrict__ bestA,
                       unsigned long long* __restrict__ bestB, int* __restrict__ flags) {
    int v = blockIdx.x * blockDim.x + threadIdx.x;
    if (v < MAX_ROUNDS) flags[v] = 0;
    if (v >= V_NODES) return;
    parent[v] = v;
    bestA[v] = ~0ULL;
    bestB[v] = ~0ULL;
}

// Round 0: endpoints ARE roots. Compute keys once, zero out[], build records,
// bid into bestA. Self-loops are born dead (a==b).
__global__ void k_scan0(const float* __restrict__ s, const float* __restrict__ u,
                        const int* __restrict__ src, const int* __restrict__ dst,
                        float* __restrict__ out, unsigned long long* __restrict__ best,
                        Rec* __restrict__ recs, int* __restrict__ flags, int E) {
    int e = blockIdx.x * blockDim.x + threadIdx.x;
    if (e >= E) return;
    unsigned int a = src[e], b = dst[e];
    Rec r;
    r.k = make_key(s[e], u[e], e);
    r.a = a; r.b = b;
    recs[e] = r;
    out[e] = 0.0f;                           // harness poisons d_out each call
    if (a != b) {
        if (r.k < __hip_atomic_load(&best[a], __ATOMIC_RELAXED, __HIP_MEMORY_SCOPE_AGENT))
            atomicMin(&best[a], r.k);
        if (r.k < __hip_atomic_load(&best[b], __ATOMIC_RELAXED, __HIP_MEMORY_SCOPE_AGENT))
            atomicMin(&best[b], r.k);
    }
    if (e == 0) flags[0] = 1;
}

// Rounds >=1. RPT records per thread; all record loads then all first-hop
// parent gathers are issued independently (MLP), then chases/bids resolve.
// Record endpoints are previous-round roots => chases are 0-1 extra hops.
__global__ void k_scan(const int* __restrict__ parent,
                       unsigned long long* __restrict__ bestC,
                       Rec* __restrict__ recs, int* __restrict__ flags,
                       int r, int E) {
    __shared__ int sflag;
    if (flags[r - 1] == 0) return;           // converged: launch-cost only
    if (threadIdx.x == 0) sflag = 0;
    __syncthreads();
    int base = (blockIdx.x * blockDim.x + threadIdx.x) * RPT;
    bool cross = false;

    Rec rec[RPT];
    int pa[RPT], pb[RPT];
    bool live[RPT];
    #pragma unroll
    for (int j = 0; j < RPT; ++j) {          // batched record loads
        int i = base + j;
        if (i < E) rec[j] = recs[i];
        else { rec[j].a = 0; rec[j].b = 0; }
        live[j] = (rec[j].a != rec[j].b);
    }
    #pragma unroll
    for (int j = 0; j < RPT; ++j)            // batched first-hop gathers
        if (live[j]) { pa[j] = parent[rec[j].a]; pb[j] = parent[rec[j].b]; }
    #pragma unroll
    for (int j = 0; j < RPT; ++j) {
        if (!live[j]) continue;
        int i = base + j;
        int ra = pa[j], rb = pb[j];
        int p = parent[ra]; while (ra != p) { ra = p; p = parent[ra]; }
        p = parent[rb];     while (rb != p) { rb = p; p = parent[rb]; }
        if (ra == rb) {
            *(uint2*)&recs[i].a = make_uint2((unsigned)ra, (unsigned)ra);  // dead
        } else {
            cross = true;
            if ((unsigned)ra != rec[j].a || (unsigned)rb != rec[j].b)
                *(uint2*)&recs[i].a = make_uint2((unsigned)ra, (unsigned)rb);
            unsigned long long k = rec[j].k;
            if (k < __hip_atomic_load(&bestC[ra], __ATOMIC_RELAXED, __HIP_MEMORY_SCOPE_AGENT))
                atomicMin(&bestC[ra], k);    // check-before-atomic
            if (k < __hip_atomic_load(&bestC[rb], __ATOMIC_RELAXED, __HIP_MEMORY_SCOPE_AGENT))
                atomicMin(&bestC[rb], k);
        }
    }
    if (cross) sflag = 1;                    // LDS race benign (same value)
    __syncthreads();
    if (threadIdx.x == 0 && sflag) flags[r] = 1;
}

// V-domain winner/hook + coalesced reset of the NEXT round's best buffer
// (bestN = B_{r+1} = B_{r-1}: dead between choose r-1 and scan r+1, so this
// is the safe slot). v's winning record is unique (key embeds edge id): mark
// the edge (cut property => in MSF) and hook v into the partner's tree.
// Mutual pair broken by root id; hook chains follow strictly decreasing keys
// => acyclic. Stale best entries resolve to a redundant out-write.
__global__ void k_choose(const int* __restrict__ src, const int* __restrict__ dst,
                         int* __restrict__ parent,
                         const unsigned long long* __restrict__ bestC,
                         unsigned long long* __restrict__ bestN,
                         float* __restrict__ out, const int* __restrict__ flags,
                         int r) {
    if (flags[r] == 0) return;               // no bids => no future rounds
    int v = blockIdx.x * blockDim.x + threadIdx.x;
    if (v >= V_NODES) return;
    bestN[v] = ~0ULL;                        // coalesced stream reset
    unsigned long long k = bestC[v];
    if (k == ~0ULL) return;
    int id = (int)(unsigned int)(k & 0xffffffffu);
    int a0 = src[id], b0 = dst[id];
    int ru = find_root(parent, a0);
    int rv = find_root(parent, b0);
    if (ru != a0) parent[a0] = ru;           // compress original-vertex chains
    if (rv != b0) parent[b0] = rv;
    int other = (ru == v) ? rv : ru;
    out[id] = 1.0f;
    if (bestC[other] != k || v > other) {    // not mutual, or id tie-break won
        if (other != v) parent[v] = other;
    }
}

extern "C" void kernel_launch(void* const* d_in, const int* in_sizes, int n_in,
                              void* d_out, int out_size, void* d_ws, size_t ws_size,
                              hipStream_t stream) {
    const float* s  = (const float*)d_in[0];
    const float* u  = (const float*)d_in[1];
    const int*   ei = (const int*)d_in[2];
    const int E = in_sizes[0];
    const int* src = ei;
    const int* dst = ei + E;
    float* out = (float*)d_out;

    char* ws = (char*)d_ws;                                      // 16B-aligned
    Rec* recs = (Rec*)ws;                                        // E*16 = 6.4 MB
    unsigned long long* bestA = (unsigned long long*)(recs + E); // V*8
    unsigned long long* bestB = bestA + V_NODES;                 // V*8
    int* parent = (int*)(bestB + V_NODES);                       // V*4
    int* flags  = parent + V_NODES;                              // MAX_ROUNDS*4
    // total ~8.4 MB

    const int gE  = (E + TB - 1) / TB;
    const int gE4 = (E + TB * RPT - 1) / (TB * RPT);
    const int gV  = (V_NODES + TB - 1) / TB;

    k_init<<<gV, TB, 0, stream>>>(parent, bestA, bestB, flags);
    k_scan0<<<gE, TB, 0, stream>>>(s, u, src, dst, out, bestA, recs, flags, E);
    // choose 0: bestC=A, reset bestN=B (already clean — harmless)
    k_choose<<<gV, TB, 0, stream>>>(src, dst, parent, bestA, bestB, out, flags, 0);

    for (int r = 1; r < MAX_ROUNDS; ++r) {
        unsigned long long* bc = (r & 1) ? bestB : bestA;   // bid target B_r
        unsigned long long* bn = (r & 1) ? bestA : bestB;   // reset B_{r+1}
        k_scan<<<gE4, TB, 0, stream>>>(parent, bc, recs, flags, r, E);
        k_choose<<<gV, TB, 0, stream>>>(src, dst, parent, bc, bn, out, flags, r);
    }
}